// Round 2
// baseline (748.204 us; speedup 1.0000x reference)
//
#include <hip/hip_runtime.h>
#include <math.h>

#define NUM_ACTION 125
#define NUM_NOUN   352
#define DD         5
#define HW         1024          // 32*32
#define S_TOT      5120          // HW * DD
#define C_TOT      2705          // (64+125+352)*5
#define CONF_CH    63

// One block per batch element.
__global__ __launch_bounds__(256) void ek_batch_loss_kernel(
    const float* __restrict__ pred,
    const int*   __restrict__ action_gt,
    const int*   __restrict__ noun_gt,
    float*       __restrict__ ws)   // ws[0..63]=action loss per b, ws[64..127]=noun
{
    const int b   = blockIdx.x;
    const int tid = threadIdx.x;
    const float* pb = pred + (size_t)b * C_TOT * HW;

    __shared__ float sv[256];
    __shared__ int   si[256];
    __shared__ float vals[NUM_NOUN];   // reused: action (125) then noun (352)
    __shared__ float sred[256];
    __shared__ int   s_best;

    // ---- Phase 1: argmax over s of confidence channel.
    // sigmoid is strictly monotone -> argmax over raw logits is identical
    // (no saturation: N(0,1) logits stay < 17.3). Tie-break on smallest s
    // == jnp.argmax first-occurrence; explicit index tracking makes the
    // result independent of per-thread processing order.
    // Conf channel d lives at channel (CONF_CH*DD + d), contiguous 1024 f32.
    // Vectorized: 1280 float4 loads across the block, 5 per thread.
    const float4* pc = (const float4*)(pb + (size_t)CONF_CH * DD * HW);
    float best  = -INFINITY;
    int   bestS = 0x7fffffff;
    #pragma unroll
    for (int it = 0; it < 5; ++it) {
        int v4  = tid + it * 256;       // 0..1279
        int e   = v4 * 4;               // element index in [0,5120)
        int d   = e >> 10;
        int pix = e & 1023;             // pix..pix+3 stay within the channel
        float4 vv = pc[v4];
        float vals4[4] = {vv.x, vv.y, vv.z, vv.w};
        #pragma unroll
        for (int j = 0; j < 4; ++j) {
            float v = vals4[j];
            int   s = (pix + j) * DD + d;   // reference flatten order (h,w,d)
            if (v > best || (v == best && s < bestS)) { best = v; bestS = s; }
        }
    }
    sv[tid] = best; si[tid] = bestS;
    __syncthreads();
    for (int off = 128; off > 0; off >>= 1) {
        if (tid < off) {
            float v2 = sv[tid + off]; int s2 = si[tid + off];
            if (v2 > sv[tid] || (v2 == sv[tid] && s2 < si[tid])) {
                sv[tid] = v2; si[tid] = s2;
            }
        }
        __syncthreads();
    }
    if (tid == 0) s_best = si[0];
    __syncthreads();

    const int sb       = s_best;
    const int d_star   = sb % DD;
    const int pix_star = sb / DD;
    // class channel c (absolute) -> pb[c*DD*HW + d_star*HW + pix_star]
    const size_t gbase = (size_t)d_star * HW + pix_star;

    // ---- Phase 2: action CE ----
    if (tid < NUM_ACTION)
        vals[tid] = pb[(size_t)(64 + tid) * DD * HW + gbase];
    __syncthreads();

    float m = -INFINITY;
    for (int a = tid; a < NUM_ACTION; a += 256) m = fmaxf(m, vals[a]);
    sred[tid] = m; __syncthreads();
    for (int off = 128; off > 0; off >>= 1) {
        if (tid < off) sred[tid] = fmaxf(sred[tid], sred[tid + off]);
        __syncthreads();
    }
    m = sred[0];
    __syncthreads();

    float ssum = 0.f;
    for (int a = tid; a < NUM_ACTION; a += 256) ssum += expf(vals[a] - m);
    sred[tid] = ssum; __syncthreads();
    for (int off = 128; off > 0; off >>= 1) {
        if (tid < off) sred[tid] += sred[tid + off];
        __syncthreads();
    }
    if (tid == 0) {
        float lse = logf(sred[0]) + m;
        int gt = action_gt[b];
        ws[b] = (lse - vals[gt]) * 0.5f;
    }
    __syncthreads();   // protect vals/sred before reuse

    // ---- Phase 3: noun CE ----
    for (int a = tid; a < NUM_NOUN; a += 256)
        vals[a] = pb[(size_t)(64 + NUM_ACTION + a) * DD * HW + gbase];
    __syncthreads();

    m = -INFINITY;
    for (int a = tid; a < NUM_NOUN; a += 256) m = fmaxf(m, vals[a]);
    sred[tid] = m; __syncthreads();
    for (int off = 128; off > 0; off >>= 1) {
        if (tid < off) sred[tid] = fmaxf(sred[tid], sred[tid + off]);
        __syncthreads();
    }
    m = sred[0];
    __syncthreads();

    ssum = 0.f;
    for (int a = tid; a < NUM_NOUN; a += 256) ssum += expf(vals[a] - m);
    sred[tid] = ssum; __syncthreads();
    for (int off = 128; off > 0; off >>= 1) {
        if (tid < off) sred[tid] += sred[tid + off];
        __syncthreads();
    }
    if (tid == 0) {
        float lse = logf(sred[0]) + m;
        int gt = noun_gt[b];
        ws[64 + b] = (lse - vals[gt]) * 0.5f;
    }
}

// Single-wave deterministic reduction over batch.
__global__ void ek_finalize_kernel(const float* __restrict__ ws,
                                   float* __restrict__ out)
{
    int t = threadIdx.x;   // 64 threads = 1 wave
    float la = ws[t];
    float ln = ws[64 + t];
    for (int off = 32; off > 0; off >>= 1) {
        la += __shfl_down(la, off);
        ln += __shfl_down(ln, off);
    }
    if (t == 0) {
        out[0] = la + ln;   // total
        out[1] = la;        // action
        out[2] = ln;        // noun
    }
}

extern "C" void kernel_launch(void* const* d_in, const int* in_sizes, int n_in,
                              void* d_out, int out_size, void* d_ws, size_t ws_size,
                              hipStream_t stream) {
    const float* pred = (const float*)d_in[0];
    const int*   agt  = (const int*)d_in[1];
    const int*   ngt  = (const int*)d_in[2];
    float* out = (float*)d_out;
    float* ws  = (float*)d_ws;

    ek_batch_loss_kernel<<<64, 256, 0, stream>>>(pred, agt, ngt, ws);
    ek_finalize_kernel<<<1, 64, 0, stream>>>(ws, out);
}

// Round 5
// 743.036 us; speedup vs baseline: 1.0070x; 1.0070x over previous
//
#include <hip/hip_runtime.h>
#include <math.h>

#define NUM_ACTION 125
#define NUM_NOUN   352
#define DD         5
#define HW         1024          // 32*32
#define S_TOT      5120          // HW * DD
#define C_TOT      2705          // (64+125+352)*5
#define CONF_CH    63

// One block (4 waves) per batch element.
__global__ __launch_bounds__(256) void ek_batch_loss_kernel(
    const float* __restrict__ pred,
    const int*   __restrict__ action_gt,
    const int*   __restrict__ noun_gt,
    float*       __restrict__ ws)   // ws[0..63]=action loss per b, ws[64..127]=noun
{
    const int b    = blockIdx.x;
    const int tid  = threadIdx.x;
    const int lane = tid & 63;
    const int wv   = tid >> 6;       // wave id 0..3
    const float* pb = pred + (size_t)b * C_TOT * HW;

    __shared__ float wbest_v[4];
    __shared__ int   wbest_s[4];
    __shared__ float sm_a[NUM_ACTION];
    __shared__ float sm_n[NUM_NOUN];

    // ---- Phase 1: argmax over s of the confidence channel.
    // sigmoid strictly monotone -> argmax on raw logits identical.
    // Explicit (v, s) tracking with min-s tie-break == jnp.argmax
    // first-occurrence, independent of processing order.
    const float4* pc = (const float4*)(pb + (size_t)CONF_CH * DD * HW);
    float best  = -INFINITY;
    int   bestS = 0x7fffffff;
    #pragma unroll
    for (int it = 0; it < 5; ++it) {
        int v4  = tid + it * 256;         // 0..1279 float4s
        int e   = v4 * 4;                 // element in [0,5120)
        int d   = e >> 10;
        int pix = e & 1023;
        float4 vv = pc[v4];
        float v4a[4] = {vv.x, vv.y, vv.z, vv.w};
        #pragma unroll
        for (int j = 0; j < 4; ++j) {
            float v = v4a[j];
            int   s = (pix + j) * DD + d; // reference flatten order (h,w,d)
            if (v > best || (v == best && s < bestS)) { best = v; bestS = s; }
        }
    }
    // wave-level argmax butterfly (no barriers)
    #pragma unroll
    for (int off = 32; off > 0; off >>= 1) {
        float v2 = __shfl_xor(best,  off);
        int   s2 = __shfl_xor(bestS, off);
        if (v2 > best || (v2 == best && s2 < bestS)) { best = v2; bestS = s2; }
    }
    if (lane == 0) { wbest_v[wv] = best; wbest_s[wv] = bestS; }
    __syncthreads();
    // every thread combines the 4 wave winners (uniform, cheap)
    best = wbest_v[0]; bestS = wbest_s[0];
    #pragma unroll
    for (int w = 1; w < 4; ++w) {
        float v2 = wbest_v[w]; int s2 = wbest_s[w];
        if (v2 > best || (v2 == best && s2 < bestS)) { best = v2; bestS = s2; }
    }
    const int d_star   = bestS % DD;
    const int pix_star = bestS / DD;
    const size_t gbase = (size_t)d_star * HW + pix_star;

    // ---- Phase 2: issue ALL 477 gathers at once (independent, one latency)
    if (tid < NUM_ACTION)
        sm_a[tid] = pb[(size_t)(64 + tid) * DD * HW + gbase];
    sm_n[tid] = pb[(size_t)(64 + NUM_ACTION + tid) * DD * HW + gbase];
    if (tid < NUM_NOUN - 256)
        sm_n[256 + tid] = pb[(size_t)(64 + NUM_ACTION + 256 + tid) * DD * HW + gbase];
    __syncthreads();

    // ---- Phase 3: concurrent CE reductions. Wave 0: action, wave 1: noun.
    if (wv == 0) {
        float v0 = sm_a[lane];
        float v1 = (lane < NUM_ACTION - 64) ? sm_a[64 + lane] : -INFINITY;
        float m  = fmaxf(v0, v1);
        #pragma unroll
        for (int off = 32; off > 0; off >>= 1) m = fmaxf(m, __shfl_xor(m, off));
        float ssum = expf(v0 - m) + ((lane < NUM_ACTION - 64) ? expf(v1 - m) : 0.f);
        #pragma unroll
        for (int off = 32; off > 0; off >>= 1) ssum += __shfl_xor(ssum, off);
        if (lane == 0) {
            float lse = logf(ssum) + m;
            ws[b] = (lse - sm_a[action_gt[b]]) * 0.5f;
        }
    } else if (wv == 1) {
        float v[6];
        float m = -INFINITY;
        #pragma unroll
        for (int k = 0; k < 6; ++k) {
            int idx = lane + 64 * k;
            v[k] = (idx < NUM_NOUN) ? sm_n[idx] : -INFINITY;
            m = fmaxf(m, v[k]);
        }
        #pragma unroll
        for (int off = 32; off > 0; off >>= 1) m = fmaxf(m, __shfl_xor(m, off));
        float ssum = 0.f;
        #pragma unroll
        for (int k = 0; k < 6; ++k) {
            int idx = lane + 64 * k;
            if (idx < NUM_NOUN) ssum += expf(v[k] - m);
        }
        #pragma unroll
        for (int off = 32; off > 0; off >>= 1) ssum += __shfl_xor(ssum, off);
        if (lane == 0) {
            float lse = logf(ssum) + m;
            ws[64 + b] = (lse - sm_n[noun_gt[b]]) * 0.5f;
        }
    }
}

// Single-wave deterministic reduction over batch.
__global__ void ek_finalize_kernel(const float* __restrict__ ws,
                                   float* __restrict__ out)
{
    int t = threadIdx.x;   // 64 threads = 1 wave
    float la = ws[t];
    float ln = ws[64 + t];
    #pragma unroll
    for (int off = 32; off > 0; off >>= 1) {
        la += __shfl_down(la, off);
        ln += __shfl_down(ln, off);
    }
    if (t == 0) {
        out[0] = la + ln;   // total
        out[1] = la;        // action
        out[2] = ln;        // noun
    }
}

extern "C" void kernel_launch(void* const* d_in, const int* in_sizes, int n_in,
                              void* d_out, int out_size, void* d_ws, size_t ws_size,
                              hipStream_t stream) {
    const float* pred = (const float*)d_in[0];
    const int*   agt  = (const int*)d_in[1];
    const int*   ngt  = (const int*)d_in[2];
    float* out = (float*)d_out;
    float* ws  = (float*)d_ws;

    ek_batch_loss_kernel<<<64, 256, 0, stream>>>(pred, agt, ngt, ws);
    ek_finalize_kernel<<<1, 64, 0, stream>>>(ws, out);
}